// Round 2
// baseline (334.351 us; speedup 1.0000x reference)
//
#include <hip/hip_runtime.h>

#define EDIM 300
#define NB   128
#define NQ   16
#define ND   1024
#define NK   11
#define DOCS_PER_BLOCK 128
#define BLOCKS_PER_B   8          // 1024 / 128
#define NCHUNK 75                 // EDIM/4 float4 chunks
#define SIMTPAD 132               // 128 docs + 4 pad (breaks pow2 stride)

// ---------------- Kernel 1: fused qnorm + sim + RBF partial sums ----------------
// grid = 1024 blocks x 256. Block = (b, 128 docs). Thread: p = tid&7 owns an
// E-eighth (9-10 float4 chunks), g = tid>>3 owns docs 4g..4g+3 (M=4 register
// blocking -> each ds_read_b128 of a q-vec feeds 16 FMAs). Partial sims are
// combined with 3-stage shfl_xor (lanes 8g+p are wave-contiguous).
__global__ __launch_bounds__(256) void knrm_main(
    const int*   __restrict__ dtoks,
    const int*   __restrict__ qtoks,
    const float* __restrict__ emb,
    const float* __restrict__ mus,
    const float* __restrict__ sigmas,
    float*       __restrict__ part) {
    __shared__ __align__(16) float qn_s[NQ * EDIM];      // 19.2 KB
    __shared__ __align__(16) float sim_t[NQ * SIMTPAD];  // 8.4 KB
    __shared__ float rs_s[NQ];

    const int blk   = blockIdx.x;
    const int b     = blk >> 3;
    const int dbase = (blk & 7) * DOCS_PER_BLOCK;
    const int tid   = threadIdx.x;

    // ---- stage raw q rows (coalesced), then normalize in-block ----
    for (int i = tid; i < NQ * EDIM; i += 256) {
        int q = i / EDIM;
        int e = i - q * EDIM;
        int tok = qtoks[b * NQ + q];
        qn_s[i] = emb[(size_t)tok * EDIM + e];
    }
    __syncthreads();
    {
        int q = tid >> 4, j = tid & 15;
        float ss = 0.f;
        for (int e = j; e < EDIM; e += 16) { float v = qn_s[q * EDIM + e]; ss += v * v; }
        ss += __shfl_xor(ss, 1, 64); ss += __shfl_xor(ss, 2, 64);
        ss += __shfl_xor(ss, 4, 64); ss += __shfl_xor(ss, 8, 64);
        if (j == 0) rs_s[q] = 1.0f / (sqrtf(ss) + 1e-9f);
    }
    __syncthreads();
    for (int i = tid; i < NQ * EDIM; i += 256)
        qn_s[i] *= rs_s[i / EDIM];
    __syncthreads();

    // ---- main compute: 4 docs/thread over an E-eighth ----
    const int p  = tid & 7;
    const int g  = tid >> 3;                 // 0..31
    const int d0 = dbase + g * 4;
    const int cstart = (p < 3) ? 10 * p : 30 + 9 * (p - 3);
    const int nch    = (p < 3) ? 10 : 9;     // 3*10 + 5*9 = 75

    int4 tks = *(const int4*)&dtoks[b * ND + d0];
    const float4* rp0 = (const float4*)(emb + (size_t)tks.x * EDIM) + cstart;
    const float4* rp1 = (const float4*)(emb + (size_t)tks.y * EDIM) + cstart;
    const float4* rp2 = (const float4*)(emb + (size_t)tks.z * EDIM) + cstart;
    const float4* rp3 = (const float4*)(emb + (size_t)tks.w * EDIM) + cstart;

    float sims[4][NQ];
#pragma unroll
    for (int m = 0; m < 4; ++m)
#pragma unroll
        for (int q = 0; q < NQ; ++q) sims[m][q] = 0.f;
    float ssq[4] = {0.f, 0.f, 0.f, 0.f};

    for (int c = 0; c < nch; ++c) {
        float4 dv0 = rp0[c], dv1 = rp1[c], dv2 = rp2[c], dv3 = rp3[c];
        ssq[0] += dv0.x*dv0.x + dv0.y*dv0.y + dv0.z*dv0.z + dv0.w*dv0.w;
        ssq[1] += dv1.x*dv1.x + dv1.y*dv1.y + dv1.z*dv1.z + dv1.w*dv1.w;
        ssq[2] += dv2.x*dv2.x + dv2.y*dv2.y + dv2.z*dv2.z + dv2.w*dv2.w;
        ssq[3] += dv3.x*dv3.x + dv3.y*dv3.y + dv3.z*dv3.z + dv3.w*dv3.w;
        const float* qb = qn_s + (cstart + c) * 4;
#pragma unroll
        for (int q = 0; q < NQ; ++q) {
            float4 qv = *(const float4*)(qb + q * EDIM);   // b128, 8 addrs/wave
            sims[0][q] += qv.x*dv0.x + qv.y*dv0.y + qv.z*dv0.z + qv.w*dv0.w;
            sims[1][q] += qv.x*dv1.x + qv.y*dv1.y + qv.z*dv1.z + qv.w*dv1.w;
            sims[2][q] += qv.x*dv2.x + qv.y*dv2.y + qv.z*dv2.z + qv.w*dv2.w;
            sims[3][q] += qv.x*dv3.x + qv.y*dv3.y + qv.z*dv3.z + qv.w*dv3.w;
        }
    }

    // ---- combine E-eighths across lanes 8g..8g+7 ----
#pragma unroll
    for (int m = 0; m < 4; ++m) {
        ssq[m] += __shfl_xor(ssq[m], 1, 64);
        ssq[m] += __shfl_xor(ssq[m], 2, 64);
        ssq[m] += __shfl_xor(ssq[m], 4, 64);
    }
#pragma unroll
    for (int m = 0; m < 4; ++m)
#pragma unroll
        for (int q = 0; q < NQ; ++q) {
            sims[m][q] += __shfl_xor(sims[m][q], 1, 64);
            sims[m][q] += __shfl_xor(sims[m][q], 2, 64);
            sims[m][q] += __shfl_xor(sims[m][q], 4, 64);
        }
    float rn[4];
#pragma unroll
    for (int m = 0; m < 4; ++m) rn[m] = 1.0f / (sqrtf(ssq[m]) + 1e-9f);

    // lane p stores q = 2p, 2p+1 (compile-time q indexing; no scratch)
#pragma unroll
    for (int q = 0; q < NQ; ++q) {
        if ((q >> 1) == p) {
            float4 v = make_float4(sims[0][q]*rn[0], sims[1][q]*rn[1],
                                   sims[2][q]*rn[2], sims[3][q]*rn[3]);
            *(float4*)&sim_t[q * SIMTPAD + g * 4] = v;
        }
    }
    __syncthreads();

    // ---- RBF bank partial sums for this block's 128 docs ----
    if (tid < NK * NQ) {
        int k = tid >> 4, q = tid & 15;
        float mu = mus[k];
        float sg = sigmas[k];
        float cc = -0.5f / (sg * sg);
        float a = 0.f;
        for (int i = 0; i < DOCS_PER_BLOCK / 4; ++i) {
            float4 s4 = *(const float4*)&sim_t[q * SIMTPAD + 4 * i];
            float e0 = s4.x - mu, e1 = s4.y - mu, e2 = s4.z - mu, e3 = s4.w - mu;
            a += __expf(cc * e0 * e0);
            a += __expf(cc * e1 * e1);
            a += __expf(cc * e2 * e2);
            a += __expf(cc * e3 * e3);
        }
        part[blk * (NK * NQ) + tid] = a;    // non-atomic per-block partial
    }
}

// ---------------- Kernel 2: sum partials, masked log-sum over q, FC ----------------
// grid = 128 blocks (one per b) x 192 threads
__global__ void knrm_final(const float* __restrict__ part,
                           const int*   __restrict__ qtoks,
                           const float* __restrict__ fc_w,
                           const float* __restrict__ fc_b,
                           float*       __restrict__ out) {
    __shared__ float red[NK * NQ];
    __shared__ float ks[NK];
    int b = blockIdx.x;
    int t = threadIdx.x;
    if (t < NK * NQ) {
        int q = t & 15;
        float r = 0.f;
        for (int j = 0; j < BLOCKS_PER_B; ++j)
            r += part[(b * BLOCKS_PER_B + j) * (NK * NQ) + t];
        red[t] = (qtoks[b * NQ + q] != 0) ? logf(r + 1e-6f) : 0.f;
    }
    __syncthreads();
    if (t < NK) {
        float s = 0.f;
        for (int q = 0; q < NQ; ++q) s += red[t * NQ + q];
        ks[t] = s * fc_w[t];
    }
    __syncthreads();
    if (t == 0) {
        float s = fc_b[0];
        for (int k = 0; k < NK; ++k) s += ks[k];
        out[b] = s;
    }
}

extern "C" void kernel_launch(void* const* d_in, const int* in_sizes, int n_in,
                              void* d_out, int out_size, void* d_ws, size_t ws_size,
                              hipStream_t stream) {
    const int*   doctoks   = (const int*)  d_in[0];   // [128,1024]
    const int*   querytoks = (const int*)  d_in[1];   // [128,16]
    // d_in[2] = query_idf: unused by the reference
    const float* emb       = (const float*)d_in[3];   // [100000,300]
    const float* mus       = (const float*)d_in[4];   // [11]
    const float* sigmas    = (const float*)d_in[5];   // [11]
    const float* fc_w      = (const float*)d_in[6];   // [1,11]
    const float* fc_b      = (const float*)d_in[7];   // [1]
    float* out = (float*)d_out;                        // [128]

    float* part = (float*)d_ws;                        // [1024][176] floats = 704 KB

    knrm_main<<<NB * BLOCKS_PER_B, 256, 0, stream>>>(doctoks, querytoks, emb,
                                                     mus, sigmas, part);
    knrm_final<<<NB, 192, 0, stream>>>(part, querytoks, fc_w, fc_b, out);
}

// Round 4
// 248.197 us; speedup vs baseline: 1.3471x; 1.3471x over previous
//
#include <hip/hip_runtime.h>

#define EDIM 300
#define NB   128
#define NQ   16
#define ND   1024
#define NK   11
#define BLOCK 128
#define MDOC  4
#define DOCS_PER_BLOCK (BLOCK * MDOC)   // 512
#define BLOCKS_PER_B   2                // 1024 / 512
#define NCHUNK 75                       // EDIM/4
#define SIMW (DOCS_PER_BLOCK + 4)       // 516 floats: breaks pow2 stride, keeps 16B align

// ---------------- Kernel 1: fused qnorm + sim + RBF partial sums ----------------
// grid = 256 blocks x 128 threads (1 block/CU). Block = (b, 512 docs).
// Thread owns M=4 WHOLE doc rows and streams them float4-sequentially from
// global (the R1 access pattern that gave 83MB FETCH). q-vectors live in LDS;
// every q read is wave-uniform (broadcast, conflict-free) and feeds 64 FMAs.
__global__ __launch_bounds__(BLOCK) void knrm_main(
    const int*   __restrict__ dtoks,
    const int*   __restrict__ qtoks,
    const float* __restrict__ emb,
    const float* __restrict__ mus,
    const float* __restrict__ sigmas,
    float*       __restrict__ part) {
    __shared__ __align__(16) float qn_s[NQ * EDIM];    // 19.2 KB
    __shared__ __align__(16) float sim_t[NQ * SIMW];   // 33.0 KB
    __shared__ float rs_s[NQ];
    __shared__ float red_s[NK * NQ * 8];               // 5.6 KB

    const int blk  = blockIdx.x;
    const int b    = blk >> 1;
    const int half = blk & 1;
    const int tid  = threadIdx.x;

    // ---- stage raw q rows (L2/L3-hot gather), normalize in-block ----
    for (int i = tid; i < NQ * EDIM; i += BLOCK) {
        int q = i / EDIM;
        int e = i - q * EDIM;
        qn_s[i] = emb[(size_t)qtoks[b * NQ + q] * EDIM + e];
    }
    __syncthreads();
    {
        int q = tid >> 3, j = tid & 7;
        float ss = 0.f;
        for (int e = j; e < EDIM; e += 8) { float v = qn_s[q * EDIM + e]; ss += v * v; }
        ss += __shfl_xor(ss, 1, 64);
        ss += __shfl_xor(ss, 2, 64);
        ss += __shfl_xor(ss, 4, 64);
        if (j == 0) rs_s[q] = 1.0f / (sqrtf(ss) + 1e-9f);
    }
    __syncthreads();
    for (int i = tid; i < NQ * EDIM; i += BLOCK) qn_s[i] *= rs_s[i / EDIM];
    __syncthreads();

    // ---- main compute: 4 whole doc rows per thread ----
    const int d0 = half * DOCS_PER_BLOCK + tid * MDOC;
    int4 tks = *(const int4*)&dtoks[b * ND + d0];
    const float4* rp0 = (const float4*)(emb + (size_t)tks.x * EDIM);
    const float4* rp1 = (const float4*)(emb + (size_t)tks.y * EDIM);
    const float4* rp2 = (const float4*)(emb + (size_t)tks.z * EDIM);
    const float4* rp3 = (const float4*)(emb + (size_t)tks.w * EDIM);

    float sims[MDOC][NQ];
#pragma unroll
    for (int m = 0; m < MDOC; ++m)
#pragma unroll
        for (int q = 0; q < NQ; ++q) sims[m][q] = 0.f;
    float ssq0 = 0.f, ssq1 = 0.f, ssq2 = 0.f, ssq3 = 0.f;

    float4 a0 = rp0[0], a1 = rp1[0], a2 = rp2[0], a3 = rp3[0];

#define KNRM_BODY(CIDX)                                                        \
    do {                                                                       \
        ssq0 += a0.x*a0.x + a0.y*a0.y + a0.z*a0.z + a0.w*a0.w;                 \
        ssq1 += a1.x*a1.x + a1.y*a1.y + a1.z*a1.z + a1.w*a1.w;                 \
        ssq2 += a2.x*a2.x + a2.y*a2.y + a2.z*a2.z + a2.w*a2.w;                 \
        ssq3 += a3.x*a3.x + a3.y*a3.y + a3.z*a3.z + a3.w*a3.w;                 \
        const float* qb = qn_s + (CIDX) * 4;                                   \
        _Pragma("unroll")                                                      \
        for (int q = 0; q < NQ; ++q) {                                         \
            float4 qv = *(const float4*)(qb + q * EDIM); /* broadcast */       \
            sims[0][q] += qv.x*a0.x + qv.y*a0.y + qv.z*a0.z + qv.w*a0.w;       \
            sims[1][q] += qv.x*a1.x + qv.y*a1.y + qv.z*a1.z + qv.w*a1.w;       \
            sims[2][q] += qv.x*a2.x + qv.y*a2.y + qv.z*a2.z + qv.w*a2.w;       \
            sims[3][q] += qv.x*a3.x + qv.y*a3.y + qv.z*a3.z + qv.w*a3.w;       \
        }                                                                      \
    } while (0)

    for (int c = 0; c < NCHUNK - 1; ++c) {
        float4 n0 = rp0[c + 1], n1 = rp1[c + 1], n2 = rp2[c + 1], n3 = rp3[c + 1];
        KNRM_BODY(c);
        a0 = n0; a1 = n1; a2 = n2; a3 = n3;
    }
    KNRM_BODY(NCHUNK - 1);
#undef KNRM_BODY

    // pad docs (tok 0): zero row -> ssq=0 -> sim=0, matches reference masking
    float rn0 = 1.0f / (sqrtf(ssq0) + 1e-9f);
    float rn1 = 1.0f / (sqrtf(ssq1) + 1e-9f);
    float rn2 = 1.0f / (sqrtf(ssq2) + 1e-9f);
    float rn3 = 1.0f / (sqrtf(ssq3) + 1e-9f);

#pragma unroll
    for (int q = 0; q < NQ; ++q) {
        *(float4*)&sim_t[q * SIMW + tid * 4] =
            make_float4(sims[0][q]*rn0, sims[1][q]*rn1, sims[2][q]*rn2, sims[3][q]*rn3);
    }
    __syncthreads();

    // ---- RBF bank: thread = (q, doc-slice s of 8), 11 k-accums in regs ----
    {
        const int q = tid & 15;
        const int s = tid >> 4;          // 0..7, 64 docs each
        float mu[NK], cc[NK], acc[NK];
#pragma unroll
        for (int k = 0; k < NK; ++k) {
            mu[k] = mus[k];
            float sg = sigmas[k];
            cc[k] = -0.5f / (sg * sg);
            acc[k] = 0.f;
        }
        const float* row = sim_t + q * SIMW + s * 64;
        for (int i = 0; i < 16; ++i) {
            float4 s4 = *(const float4*)(row + i * 4);
#pragma unroll
            for (int k = 0; k < NK; ++k) {
                float e0 = s4.x - mu[k], e1 = s4.y - mu[k];
                float e2 = s4.z - mu[k], e3 = s4.w - mu[k];
                acc[k] += __expf(cc[k]*e0*e0) + __expf(cc[k]*e1*e1)
                        + __expf(cc[k]*e2*e2) + __expf(cc[k]*e3*e3);
            }
        }
#pragma unroll
        for (int k = 0; k < NK; ++k) red_s[(k * NQ + q) * 8 + s] = acc[k];
    }
    __syncthreads();

    // BUGFIX R3->R4: NK*NQ = 176 > BLOCK = 128; the old `if (tid < 176)` left
    // entries 128..175 (k=8..10) unwritten (0xAA poison). Stride the write.
    for (int t = tid; t < NK * NQ; t += BLOCK) {
        float r = 0.f;
#pragma unroll
        for (int j = 0; j < 8; ++j) r += red_s[t * 8 + j];
        part[blk * (NK * NQ) + t] = r;   // non-atomic per-block partial
    }
}

// ---------------- Kernel 2: sum partials, masked log-sum over q, FC ----------------
__global__ void knrm_final(const float* __restrict__ part,
                           const int*   __restrict__ qtoks,
                           const float* __restrict__ fc_w,
                           const float* __restrict__ fc_b,
                           float*       __restrict__ out) {
    __shared__ float red[NK * NQ];
    __shared__ float ks[NK];
    int b = blockIdx.x;
    int t = threadIdx.x;
    if (t < NK * NQ) {
        int q = t & 15;
        float r = 0.f;
        for (int j = 0; j < BLOCKS_PER_B; ++j)
            r += part[(b * BLOCKS_PER_B + j) * (NK * NQ) + t];
        red[t] = (qtoks[b * NQ + q] != 0) ? logf(r + 1e-6f) : 0.f;
    }
    __syncthreads();
    if (t < NK) {
        float s = 0.f;
        for (int q = 0; q < NQ; ++q) s += red[t * NQ + q];
        ks[t] = s * fc_w[t];
    }
    __syncthreads();
    if (t == 0) {
        float s = fc_b[0];
        for (int k = 0; k < NK; ++k) s += ks[k];
        out[b] = s;
    }
}

extern "C" void kernel_launch(void* const* d_in, const int* in_sizes, int n_in,
                              void* d_out, int out_size, void* d_ws, size_t ws_size,
                              hipStream_t stream) {
    const int*   doctoks   = (const int*)  d_in[0];   // [128,1024]
    const int*   querytoks = (const int*)  d_in[1];   // [128,16]
    // d_in[2] = query_idf: unused by the reference
    const float* emb       = (const float*)d_in[3];   // [100000,300]
    const float* mus       = (const float*)d_in[4];   // [11]
    const float* sigmas    = (const float*)d_in[5];   // [11]
    const float* fc_w      = (const float*)d_in[6];   // [1,11]
    const float* fc_b      = (const float*)d_in[7];   // [1]
    float* out = (float*)d_out;                        // [128]

    float* part = (float*)d_ws;                        // [256][176] floats

    knrm_main<<<NB * BLOCKS_PER_B, BLOCK, 0, stream>>>(doctoks, querytoks, emb,
                                                       mus, sigmas, part);
    knrm_final<<<NB, 192, 0, stream>>>(part, querytoks, fc_w, fc_b, out);
}